// Round 6
// baseline (901.209 us; speedup 1.0000x reference)
//
#include <hip/hip_runtime.h>
#include <hip/hip_fp16.h>

#define K_NB 81
#define OUTC 8
#define BLK 256
#define KT 16   // k-tile; 80 = 5*16 (k=0 handled in prologue)
#define NTL 5   // number of tiles

typedef float v2f __attribute__((ext_vector_type(2)));

// W2[k][c][l] = dw[k][c] * weight[c][k][l], flat as w2[k*32 + c*8 + l]
__global__ void prep_w2(const float* __restrict__ dw,
                        const float* __restrict__ wt,
                        float* __restrict__ w2) {
    int i = blockIdx.x * blockDim.x + threadIdx.x;
    if (i < K_NB * 32) {
        int k = i >> 5;
        int c = (i >> 3) & 3;
        int l = i & 7;
        w2[i] = dw[k * 4 + c] * wt[(c * K_NB + k) * OUTC + l];
    }
}

union F2H { float f; __half2 h; };

// points [N,3] fp32 -> ph[N] = {half x, half y, half z, half 0} (8B, aligned)
__global__ void repack_points(const float* __restrict__ pts,
                              v2f* __restrict__ ph, int N) {
    int n = blockIdx.x * blockDim.x + threadIdx.x;
    if (n >= N) return;
    float x = pts[3 * n + 0], y = pts[3 * n + 1], z = pts[3 * n + 2];
    F2H a, b;
    a.h = __floats2half2_rn(x, y);
    b.h = __floats2half2_rn(z, 0.f);
    v2f v; v.x = a.f; v.y = b.f;
    ph[n] = v;
}

__global__ __launch_bounds__(BLK) void conv_main_h(
    const float* __restrict__ points,   // fp32, coalesced self-load
    const v2f*   __restrict__ ph,       // half4-packed points (4 MB, L2-resident)
    const int*   __restrict__ indices,
    const float* __restrict__ w2,
    const float* __restrict__ bias,
    float*       __restrict__ out,
    int N) {
    __shared__ int sidx[BLK * (KT + 1)];  // pitch 17: 2-way bank alias = free

    const int tid = threadIdx.x;
    const int n0  = blockIdx.x * BLK;
    const int n   = n0 + tid;
    const bool valid = n < N;
    const int nc = valid ? n : (N - 1);

    // staging pattern: element e = i*256+tid -> row = i*16 + (tid>>4),
    // col = tid&15 (16-lane 64B-contiguous runs in global memory)
    const int srow = tid >> 4;
    const int scol = tid & 15;

    const float px = points[nc * 3 + 0];
    const float py = points[nc * 3 + 1];
    const float pz = points[nc * 3 + 2];

    float acc[OUTC];
#pragma unroll
    for (int l = 0; l < OUTC; ++l) {
        float a = bias[l] + w2[24 + l];           // k=0: dist feature = 1.0
        a = fmaf(px, w2[0 + l], a);
        a = fmaf(py, w2[8 + l], a);
        a = fmaf(pz, w2[16 + l], a);
        acc[l] = a;
    }

    // index address helper (clamped row so every slot is a valid index).
    // nt on INDEX loads only: 162 MB stream-once, keep out of L2 so the
    // 4 MB ph stays resident (R4 lesson: never nt the reused gather data).
    auto idx_ld = [&](int t, int i) -> int {
        int gr = n0 + i * 16 + srow;
        if (gr >= N) gr = N - 1;
        return __builtin_nontemporal_load(
            &indices[gr * K_NB + 1 + t * KT + scol]);
    };

    int ireg[KT];
    v2f r_cur[KT];

    // ---- prologue: tile0 ids -> LDS -> gathers; prefetch tile1 ids ----
#pragma unroll
    for (int i = 0; i < KT; ++i) ireg[i] = idx_ld(0, i);
#pragma unroll
    for (int i = 0; i < KT; ++i)
        sidx[(i * 16 + srow) * (KT + 1) + scol] = ireg[i];
    __syncthreads();
    // issue NEXT tile's index loads FIRST (older in vmcnt order), so the
    // ds_write wait next iteration leaves the gathers below in flight.
#pragma unroll
    for (int i = 0; i < KT; ++i) ireg[i] = idx_ld(1, i);
#pragma unroll
    for (int j = 0; j < KT; ++j) r_cur[j] = ph[sidx[tid * (KT + 1) + j]];

    // ---- pipelined main loop: gathers for t+1 in flight while consuming t ----
#pragma unroll
    for (int t = 0; t < NTL; ++t) {
        v2f r_nxt[KT];
        if (t < NTL - 1) {
            __syncthreads();                       // everyone done reading LDS
#pragma unroll
            for (int i = 0; i < KT; ++i)           // waits ireg only (vmcnt(16))
                sidx[(i * 16 + srow) * (KT + 1) + scol] = ireg[i];
            if (t < NTL - 2) {
#pragma unroll
                for (int i = 0; i < KT; ++i) ireg[i] = idx_ld(t + 2, i);
            }
            __syncthreads();
#pragma unroll
            for (int j = 0; j < KT; ++j)
                r_nxt[j] = ph[sidx[tid * (KT + 1) + j]];
        }

        // consume tile t while tile t+1's gathers are in flight
#pragma unroll
        for (int j = 0; j < KT; ++j) {
            const int k = 1 + t * KT + j;
            F2H u0, u1; u0.f = r_cur[j].x; u1.f = r_cur[j].y;
            const float2 fxy = __half22float2(u0.h);
            const float  qx = fxy.x, qy = fxy.y;
            const float  qz = __half2float(__low2half(u1.h));
            const float dx = qx - px, dy = qy - py, dz = qz - pz;
            const float dist = fmaf(dx, dx, fmaf(dy, dy, fmaf(dz, dz, 1.0f)));
            const float* __restrict__ w = w2 + k * 32;  // uniform -> s_load
#pragma unroll
            for (int l = 0; l < OUTC; ++l) {
                acc[l] = fmaf(qx, w[l],
                         fmaf(qy, w[8 + l],
                         fmaf(qz, w[16 + l],
                         fmaf(dist, w[24 + l], acc[l]))));
            }
        }

        if (t < NTL - 1) {
#pragma unroll
            for (int j = 0; j < KT; ++j) r_cur[j] = r_nxt[j];
        }
    }

    if (valid) {
        float4* o = (float4*)(out + (long)n * OUTC);
        o[0] = make_float4(acc[0], acc[1], acc[2], acc[3]);
        o[1] = make_float4(acc[4], acc[5], acc[6], acc[7]);
    }
}

// ---------- fp32 fallback if ws too small ----------
__global__ __launch_bounds__(BLK) void conv_main_f32(
    const float* __restrict__ points,
    const int*   __restrict__ indices,
    const float* __restrict__ w2,
    const float* __restrict__ bias,
    float*       __restrict__ out,
    int N) {
    __shared__ int sidx[BLK * (KT + 1)];
    const int tid = threadIdx.x;
    const int n0  = blockIdx.x * BLK;
    const int n   = n0 + tid;
    const bool valid = n < N;
    const int nc = valid ? n : (N - 1);

    const float px = points[nc * 3 + 0];
    const float py = points[nc * 3 + 1];
    const float pz = points[nc * 3 + 2];
    float acc[OUTC];
#pragma unroll
    for (int l = 0; l < OUTC; ++l) {
        float a = bias[l] + w2[24 + l];
        a = fmaf(px, w2[0 + l], a);
        a = fmaf(py, w2[8 + l], a);
        a = fmaf(pz, w2[16 + l], a);
        acc[l] = a;
    }
    for (int t = 0; t < NTL; ++t) {
        __syncthreads();
#pragma unroll
        for (int i = 0; i < KT; ++i) {
            int e = i * BLK + tid;
            int row = e >> 4, col = e & 15;
            int gr = n0 + row;
            if (gr >= N) gr = N - 1;
            sidx[row * (KT + 1) + col] = indices[gr * K_NB + 1 + t * KT + col];
        }
        __syncthreads();
#pragma unroll
        for (int j = 0; j < KT; ++j) {
            const int k  = 1 + t * KT + j;
            const int id = sidx[tid * (KT + 1) + j];
            const float qx = points[id * 3 + 0];
            const float qy = points[id * 3 + 1];
            const float qz = points[id * 3 + 2];
            const float dx = qx - px, dy = qy - py, dz = qz - pz;
            const float dist = fmaf(dx, dx, fmaf(dy, dy, fmaf(dz, dz, 1.0f)));
            const float* __restrict__ w = w2 + k * 32;
#pragma unroll
            for (int l = 0; l < OUTC; ++l) {
                acc[l] = fmaf(qx, w[l],
                         fmaf(qy, w[8 + l],
                         fmaf(qz, w[16 + l],
                         fmaf(dist, w[24 + l], acc[l]))));
            }
        }
    }
    if (valid) {
        float4* o = (float4*)(out + (long)n * OUTC);
        o[0] = make_float4(acc[0], acc[1], acc[2], acc[3]);
        o[1] = make_float4(acc[4], acc[5], acc[6], acc[7]);
    }
}

extern "C" void kernel_launch(void* const* d_in, const int* in_sizes, int n_in,
                              void* d_out, int out_size, void* d_ws, size_t ws_size,
                              hipStream_t stream) {
    const float* points  = (const float*)d_in[0];
    const int*   indices = (const int*)  d_in[1];
    const float* dw      = (const float*)d_in[2];
    const float* wt      = (const float*)d_in[3];
    const float* bias    = (const float*)d_in[4];
    float*       out     = (float*)d_out;

    const int N = in_sizes[0] / 3;

    const size_t ph_bytes = (size_t)N * 8;
    const size_t need     = ph_bytes + K_NB * 32 * sizeof(float);

    if (ws_size >= need) {
        v2f*   ph = (v2f*)d_ws;
        float* w2 = (float*)((char*)d_ws + ph_bytes);
        hipLaunchKernelGGL(prep_w2, dim3((K_NB * 32 + BLK - 1) / BLK), dim3(BLK),
                           0, stream, dw, wt, w2);
        hipLaunchKernelGGL(repack_points, dim3((N + BLK - 1) / BLK), dim3(BLK),
                           0, stream, points, ph, N);
        hipLaunchKernelGGL(conv_main_h, dim3((N + BLK - 1) / BLK), dim3(BLK),
                           0, stream, points, ph, indices, w2, bias, out, N);
    } else {
        float* w2 = (float*)d_ws;
        hipLaunchKernelGGL(prep_w2, dim3((K_NB * 32 + BLK - 1) / BLK), dim3(BLK),
                           0, stream, dw, wt, w2);
        hipLaunchKernelGGL(conv_main_f32, dim3((N + BLK - 1) / BLK), dim3(BLK),
                           0, stream, points, indices, w2, bias, out, N);
    }
}

// Round 7
// 481.004 us; speedup vs baseline: 1.8736x; 1.8736x over previous
//
#include <hip/hip_runtime.h>
#include <hip/hip_fp16.h>

#define K_NB 81
#define OUTC 8
#define BLK 256
#define KT 8     // pipeline quantum; 81 = 1 + 10*8
#define NTL 10
#define PITCH 9  // LDS row pitch: stride-9 reads = 2-way bank alias = free

typedef float v2f __attribute__((ext_vector_type(2)));

// W2[k][c][l] = dw[k][c] * weight[c][k][l], flat as w2[k*32 + c*8 + l]
__global__ void prep_w2(const float* __restrict__ dw,
                        const float* __restrict__ wt,
                        float* __restrict__ w2) {
    int i = blockIdx.x * blockDim.x + threadIdx.x;
    if (i < K_NB * 32) {
        int k = i >> 5;
        int c = (i >> 3) & 3;
        int l = i & 7;
        w2[i] = dw[k * 4 + c] * wt[(c * K_NB + k) * OUTC + l];
    }
}

union F2H { float f; __half2 h; };

// points [N,3] fp32 -> ph[N] = {half x, half y, half z, half 0} (8B, aligned)
__global__ void repack_points(const float* __restrict__ pts,
                              v2f* __restrict__ ph, int N) {
    int n = blockIdx.x * blockDim.x + threadIdx.x;
    if (n >= N) return;
    float x = pts[3 * n + 0], y = pts[3 * n + 1], z = pts[3 * n + 2];
    F2H a, b;
    a.h = __floats2half2_rn(x, y);
    b.h = __floats2half2_rn(z, 0.f);
    v2f v; v.x = a.f; v.y = b.f;
    ph[n] = v;
}

// launch_bounds (256,3): >=3 blocks/CU (12 waves) AND caps VGPR ~170 so the
// pipeline state (ireg8 + r_cur16 + r_nxt16 + acc8 ~= 90 VGPR) cannot spill.
// (R6 lesson: KT=16 triple-buffer state -> 256 VGPR + 460 MB scratch spills.)
__global__ __launch_bounds__(BLK, 3) void conv_main_h(
    const float* __restrict__ points,   // fp32, coalesced self-load
    const v2f*   __restrict__ ph,       // half4-packed points (4 MB, L2-resident)
    const int*   __restrict__ indices,
    const float* __restrict__ w2,
    const float* __restrict__ bias,
    float*       __restrict__ out,
    int N) {
    __shared__ int sidx[2][BLK * PITCH];   // double-buffered index tiles

    const int tid = threadIdx.x;
    const int n0  = blockIdx.x * BLK;
    const int n   = n0 + tid;
    const bool valid = n < N;
    const int nc = valid ? n : (N - 1);

    // staging: element e = i*256+tid -> row = i*32 + (tid>>3), col = tid&7
    // (8-lane 32B-contiguous runs in global memory)
    const int srow = tid >> 3;
    const int scol = tid & 7;

    const float px = points[nc * 3 + 0];
    const float py = points[nc * 3 + 1];
    const float pz = points[nc * 3 + 2];

    float acc[OUTC];
#pragma unroll
    for (int l = 0; l < OUTC; ++l) {
        float a = bias[l] + w2[24 + l];           // k=0: dist feature = 1.0
        a = fmaf(px, w2[0 + l], a);
        a = fmaf(py, w2[8 + l], a);
        a = fmaf(pz, w2[16 + l], a);
        acc[l] = a;
    }

    // nt on INDEX loads only (162 MB stream-once; protects ph's L2 residency.
    // R4 lesson: never nt the reused gather data).
    auto idx_ld = [&](int t, int i) -> int {
        int gr = n0 + i * 32 + srow;
        if (gr >= N) gr = N - 1;
        return __builtin_nontemporal_load(
            &indices[gr * K_NB + 1 + t * KT + scol]);
    };

    int ireg[KT];
    v2f r_cur[KT];

    // ---- prologue ----
#pragma unroll
    for (int i = 0; i < KT; ++i) ireg[i] = idx_ld(0, i);
#pragma unroll
    for (int i = 0; i < KT; ++i)
        sidx[0][(i * 32 + srow) * PITCH + scol] = ireg[i];
    // tile-1 idx loads issued BEFORE the gathers below: all later waits on
    // ireg are then vmcnt-granular and never drain the gather queue.
#pragma unroll
    for (int i = 0; i < KT; ++i) ireg[i] = idx_ld(1, i);
    __syncthreads();
#pragma unroll
    for (int j = 0; j < KT; ++j)
        r_cur[j] = ph[sidx[0][tid * PITCH + j]];

    // ---- steady state: consume tile t while tile t+1's gathers + tile t+2's
    //      index loads are in flight (r_cur = oldest vmem -> granular waits) ----
#pragma unroll
    for (int t = 0; t < NTL; ++t) {
        v2f r_nxt[KT];
        if (t < NTL - 1) {
            const int b = (t + 1) & 1;
#pragma unroll
            for (int i = 0; i < KT; ++i)                 // waits ireg only
                sidx[b][(i * 32 + srow) * PITCH + scol] = ireg[i];
            if (t < NTL - 2) {
#pragma unroll
                for (int i = 0; i < KT; ++i) ireg[i] = idx_ld(t + 2, i);
            }
            __syncthreads();
#pragma unroll
            for (int j = 0; j < KT; ++j)
                r_nxt[j] = ph[sidx[b][tid * PITCH + j]];
        }

        // consume tile t (gathers issued one full iteration ago)
#pragma unroll
        for (int j = 0; j < KT; ++j) {
            const int k = 1 + t * KT + j;
            F2H u0, u1; u0.f = r_cur[j].x; u1.f = r_cur[j].y;
            const float2 fxy = __half22float2(u0.h);
            const float  qx = fxy.x, qy = fxy.y;
            const float  qz = __half2float(__low2half(u1.h));
            const float dx = qx - px, dy = qy - py, dz = qz - pz;
            const float dist = fmaf(dx, dx, fmaf(dy, dy, fmaf(dz, dz, 1.0f)));
            const float* __restrict__ w = w2 + k * 32;   // uniform -> s_load
#pragma unroll
            for (int l = 0; l < OUTC; ++l) {
                acc[l] = fmaf(qx, w[l],
                         fmaf(qy, w[8 + l],
                         fmaf(qz, w[16 + l],
                         fmaf(dist, w[24 + l], acc[l]))));
            }
        }

        if (t < NTL - 1) {
#pragma unroll
            for (int j = 0; j < KT; ++j) r_cur[j] = r_nxt[j];   // rename only
        }
    }

    if (valid) {
        float4* o = (float4*)(out + (long)n * OUTC);
        o[0] = make_float4(acc[0], acc[1], acc[2], acc[3]);
        o[1] = make_float4(acc[4], acc[5], acc[6], acc[7]);
    }
}

// ---------- fp32 fallback if ws too small (R5 structure, KT=16) ----------
__global__ __launch_bounds__(BLK) void conv_main_f32(
    const float* __restrict__ points,
    const int*   __restrict__ indices,
    const float* __restrict__ w2,
    const float* __restrict__ bias,
    float*       __restrict__ out,
    int N) {
    __shared__ int sidx[BLK * 17];
    const int tid = threadIdx.x;
    const int n0  = blockIdx.x * BLK;
    const int n   = n0 + tid;
    const bool valid = n < N;
    const int nc = valid ? n : (N - 1);

    const float px = points[nc * 3 + 0];
    const float py = points[nc * 3 + 1];
    const float pz = points[nc * 3 + 2];
    float acc[OUTC];
#pragma unroll
    for (int l = 0; l < OUTC; ++l) {
        float a = bias[l] + w2[24 + l];
        a = fmaf(px, w2[0 + l], a);
        a = fmaf(py, w2[8 + l], a);
        a = fmaf(pz, w2[16 + l], a);
        acc[l] = a;
    }
    for (int t = 0; t < 5; ++t) {
        __syncthreads();
#pragma unroll
        for (int i = 0; i < 16; ++i) {
            int e = i * BLK + tid;
            int row = e >> 4, col = e & 15;
            int gr = n0 + row;
            if (gr >= N) gr = N - 1;
            sidx[row * 17 + col] = indices[gr * K_NB + 1 + t * 16 + col];
        }
        __syncthreads();
#pragma unroll
        for (int j = 0; j < 16; ++j) {
            const int k  = 1 + t * 16 + j;
            const int id = sidx[tid * 17 + j];
            const float qx = points[id * 3 + 0];
            const float qy = points[id * 3 + 1];
            const float qz = points[id * 3 + 2];
            const float dx = qx - px, dy = qy - py, dz = qz - pz;
            const float dist = fmaf(dx, dx, fmaf(dy, dy, fmaf(dz, dz, 1.0f)));
            const float* __restrict__ w = w2 + k * 32;
#pragma unroll
            for (int l = 0; l < OUTC; ++l) {
                acc[l] = fmaf(qx, w[l],
                         fmaf(qy, w[8 + l],
                         fmaf(qz, w[16 + l],
                         fmaf(dist, w[24 + l], acc[l]))));
            }
        }
    }
    if (valid) {
        float4* o = (float4*)(out + (long)n * OUTC);
        o[0] = make_float4(acc[0], acc[1], acc[2], acc[3]);
        o[1] = make_float4(acc[4], acc[5], acc[6], acc[7]);
    }
}

extern "C" void kernel_launch(void* const* d_in, const int* in_sizes, int n_in,
                              void* d_out, int out_size, void* d_ws, size_t ws_size,
                              hipStream_t stream) {
    const float* points  = (const float*)d_in[0];
    const int*   indices = (const int*)  d_in[1];
    const float* dw      = (const float*)d_in[2];
    const float* wt      = (const float*)d_in[3];
    const float* bias    = (const float*)d_in[4];
    float*       out     = (float*)d_out;

    const int N = in_sizes[0] / 3;

    const size_t ph_bytes = (size_t)N * 8;
    const size_t need     = ph_bytes + K_NB * 32 * sizeof(float);

    if (ws_size >= need) {
        v2f*   ph = (v2f*)d_ws;
        float* w2 = (float*)((char*)d_ws + ph_bytes);
        hipLaunchKernelGGL(prep_w2, dim3((K_NB * 32 + BLK - 1) / BLK), dim3(BLK),
                           0, stream, dw, wt, w2);
        hipLaunchKernelGGL(repack_points, dim3((N + BLK - 1) / BLK), dim3(BLK),
                           0, stream, points, ph, N);
        hipLaunchKernelGGL(conv_main_h, dim3((N + BLK - 1) / BLK), dim3(BLK),
                           0, stream, points, ph, indices, w2, bias, out, N);
    } else {
        float* w2 = (float*)d_ws;
        hipLaunchKernelGGL(prep_w2, dim3((K_NB * 32 + BLK - 1) / BLK), dim3(BLK),
                           0, stream, dw, wt, w2);
        hipLaunchKernelGGL(conv_main_f32, dim3((N + BLK - 1) / BLK), dim3(BLK),
                           0, stream, points, indices, w2, bias, out, N);
    }
}